// Round 3
// baseline (1688.467 us; speedup 1.0000x reference)
//
#include <hip/hip_runtime.h>

#define F 64
#define TPB 256
#define BN_EPS 1e-5f

// f32 copy: dst = src (GIN self term; also fully initializes aggr)
__global__ void k_copy_f(const float* __restrict__ src, float* __restrict__ dst, int n) {
    int idx = blockIdx.x * blockDim.x + threadIdx.x;
    if (idx < n) dst[idx] = src[idx];
}

// aggr[dst] += h[src] over all edges; thread = (edge, feature); wave = 1 edge
__global__ void k_scatter(const int* __restrict__ src, const int* __restrict__ dst,
                          const float* __restrict__ h, float* __restrict__ aggr, int E) {
    int idx = blockIdx.x * blockDim.x + threadIdx.x;
    if (idx >= E * F) return;
    int e = idx >> 6, f = idx & 63;
    int s = src[e], d = dst[e];
    atomicAdd(&aggr[d * F + f], h[s * F + f]);
}

// Yf = A @ W + (initFlag ? bias : Yf)  -- incremental jumping-knowledge head GEMM
__global__ void k_accmm(const float* __restrict__ A, const float* __restrict__ W,
                        const float* __restrict__ bias, float* __restrict__ Yf,
                        int N, int initFlag) {
    __shared__ float Wl[F * F];
    int t = threadIdx.x;
    for (int i = t; i < F * F; i += TPB) Wl[i] = W[i];
    __syncthreads();
    int j = t & 63, r0 = t >> 6;
    int rowbase = blockIdx.x * 64;
    float bj = bias[j];
    for (int r = r0; r < 64; r += 4) {
        int row = rowbase + r;
        if (row >= N) break;
        const float* a = A + row * F;
        float acc = initFlag ? bj : Yf[row * F + j];
#pragma unroll
        for (int f = 0; f < F; ++f) acc += a[f] * Wl[f * F + j];
        Yf[row * F + j] = acc;
    }
}

// Y = A @ W + b  (A [N,64] f32, W [64,64] f32); accumulates BN column stats
__global__ void k_gemm1(const float* __restrict__ A, const float* __restrict__ W,
                        const float* __restrict__ bias, float* __restrict__ Y,
                        float* __restrict__ stats, int N) {
    __shared__ float Wl[F * F];
    __shared__ float red[TPB];
    int t = threadIdx.x;
    for (int i = t; i < F * F; i += TPB) Wl[i] = W[i];
    __syncthreads();
    int j = t & 63, r0 = t >> 6;
    int rowbase = blockIdx.x * 64;
    float bj = bias[j];
    float s1 = 0.f, s2 = 0.f;
    for (int r = r0; r < 64; r += 4) {
        int row = rowbase + r;
        if (row >= N) break;
        const float* a = A + row * F;
        float acc = bj;
#pragma unroll
        for (int f = 0; f < F; ++f) acc += a[f] * Wl[f * F + j];
        Y[row * F + j] = acc;
        s1 += acc;
        s2 += acc * acc;
    }
    red[t] = s1; __syncthreads();
    if (r0 == 0) atomicAdd(&stats[j], red[j] + red[64 + j] + red[128 + j] + red[192 + j]);
    __syncthreads();
    red[t] = s2; __syncthreads();
    if (r0 == 0) atomicAdd(&stats[64 + j], red[j] + red[64 + j] + red[128 + j] + red[192 + j]);
}

// BN(Y)+ReLU -> @W2 + b2 -> ReLU -> Hout [N,64]
__global__ void k_bn_gemm2(const float* __restrict__ Y, const float* __restrict__ stats,
                           const float* __restrict__ g, const float* __restrict__ bt,
                           const float* __restrict__ W2, const float* __restrict__ b2v,
                           float* __restrict__ Hout, int N) {
    __shared__ float Wl[F * F];
    __shared__ float Al[64 * F];
    __shared__ float scale[F], shift[F];
    int t = threadIdx.x;
    for (int i = t; i < F * F; i += TPB) Wl[i] = W2[i];
    if (t < F) {
        float mu = stats[t] / (float)N;
        float var = stats[64 + t] / (float)N - mu * mu;
        float rs = rsqrtf(var + BN_EPS);
        float sc = rs * g[t];
        scale[t] = sc;
        shift[t] = bt[t] - mu * sc;
    }
    __syncthreads();
    int j = t & 63, r0 = t >> 6;
    int rowbase = blockIdx.x * 64;
    for (int r = r0; r < 64; r += 4) {
        int row = rowbase + r;
        float v = 0.f;
        if (row < N) v = fmaxf(Y[row * F + j] * scale[j] + shift[j], 0.f);
        Al[r * F + j] = v;
    }
    __syncthreads();
    float bj = b2v[j];
    for (int r = r0; r < 64; r += 4) {
        int row = rowbase + r;
        if (row >= N) break;
        float acc = bj;
#pragma unroll
        for (int f = 0; f < F; ++f) acc += Al[r * F + f] * Wl[f * F + j];
        Hout[row * F + j] = fmaxf(acc, 0.f);
    }
}

// column sum / sumsq of A [N,64] -> stats[0:64], stats[64:128]
__global__ void k_colstats(const float* __restrict__ A, float* __restrict__ stats, int N) {
    __shared__ float red[TPB];
    int t = threadIdx.x;
    int j = t & 63, r0 = t >> 6;
    int rowbase = blockIdx.x * 64;
    float s1 = 0.f, s2 = 0.f;
    for (int r = r0; r < 64; r += 4) {
        int row = rowbase + r;
        if (row >= N) break;
        float v = A[row * F + j];
        s1 += v;
        s2 += v * v;
    }
    red[t] = s1; __syncthreads();
    if (r0 == 0) atomicAdd(&stats[j], red[j] + red[64 + j] + red[128 + j] + red[192 + j]);
    __syncthreads();
    red[t] = s2; __syncthreads();
    if (r0 == 0) atomicAdd(&stats[64 + j], red[j] + red[64 + j] + red[128 + j] + red[192 + j]);
}

// BN(Yf)+ReLU -> @W2 + b2 -> atomicAdd pool[batch[row]]
__global__ void k_final(const float* __restrict__ Yf, const float* __restrict__ stats,
                        const float* __restrict__ g, const float* __restrict__ bt,
                        const float* __restrict__ W2, const float* __restrict__ b2v,
                        const int* __restrict__ batch, float* __restrict__ pool, int N) {
    __shared__ float Wl[F * F];
    __shared__ float Al[64 * F];
    __shared__ float scale[F], shift[F];
    int t = threadIdx.x;
    for (int i = t; i < F * F; i += TPB) Wl[i] = W2[i];
    if (t < F) {
        float mu = stats[t] / (float)N;
        float var = stats[64 + t] / (float)N - mu * mu;
        float rs = rsqrtf(var + BN_EPS);
        float sc = rs * g[t];
        scale[t] = sc;
        shift[t] = bt[t] - mu * sc;
    }
    __syncthreads();
    int j = t & 63, r0 = t >> 6;
    int rowbase = blockIdx.x * 64;
    for (int r = r0; r < 64; r += 4) {
        int row = rowbase + r;
        float v = 0.f;
        if (row < N) v = fmaxf(Yf[row * F + j] * scale[j] + shift[j], 0.f);
        Al[r * F + j] = v;
    }
    __syncthreads();
    float bj = b2v[j];
    for (int r = r0; r < 64; r += 4) {
        int row = rowbase + r;
        if (row >= N) break;
        float acc = bj;
#pragma unroll
        for (int f = 0; f < F; ++f) acc += Al[r * F + f] * Wl[f * F + j];
        atomicAdd(&pool[batch[row] * F + j], acc);
    }
}

__global__ void k_out(const float* __restrict__ pool, float* __restrict__ out, int M) {
    int i = blockIdx.x * blockDim.x + threadIdx.x;
    if (i < M) out[i] = pool[i];
}

extern "C" void kernel_launch(void* const* d_in, const int* in_sizes, int n_in,
                              void* d_out, int out_size, void* d_ws, size_t ws_size,
                              hipStream_t stream) {
    const float* x      = (const float*)d_in[0];
    const int*   ei     = (const int*)d_in[1];
    const int*   batch  = (const int*)d_in[2];
    const float* convW1 = (const float*)d_in[3];
    const float* convb1 = (const float*)d_in[4];
    const float* convg  = (const float*)d_in[5];
    const float* convbt = (const float*)d_in[6];
    const float* convW2 = (const float*)d_in[7];
    const float* convb2 = (const float*)d_in[8];
    const float* mlpW1  = (const float*)d_in[9];
    const float* mlpb1  = (const float*)d_in[10];
    const float* mlpg   = (const float*)d_in[11];
    const float* mlpbt  = (const float*)d_in[12];
    const float* mlpW2  = (const float*)d_in[13];
    const float* mlpb2  = (const float*)d_in[14];

    const int N = in_sizes[0] / F;             // 50000
    const int E = in_sizes[1] / 2;             // 800000
    const int L = in_sizes[3] / (F * F);       // 5
    const int G = out_size / F;                // 256

    const int* src = ei;
    const int* dst = ei + E;

    // workspace: 4 x [N,64] fp32 + stats + pool  (~51.3 MB)
    char* w = (char*)d_ws;
    size_t off = 0;
    auto alloc = [&](size_t bytes) {
        void* p = w + off;
        off = (off + bytes + 255) & ~(size_t)255;
        return p;
    };
    float* h     = (float*)alloc((size_t)N * F * 4);
    float* aggr  = (float*)alloc((size_t)N * F * 4);
    float* Ytmp  = (float*)alloc((size_t)N * F * 4);
    float* Yf    = (float*)alloc((size_t)N * F * 4);
    float* stats = (float*)alloc((size_t)(L + 1) * 128 * 4);
    float* pool  = (float*)alloc((size_t)G * F * 4);

    hipMemsetAsync(stats, 0, (size_t)(L + 1) * 128 * 4, stream);
    hipMemsetAsync(pool, 0, (size_t)G * F * 4, stream);

    const int elemBlocks = (N * F + TPB - 1) / TPB;
    const int edgeBlocks = (E * F + TPB - 1) / TPB;
    const int rowBlocks  = (N + 63) / 64;

    // h = x (fp32 copy)
    k_copy_f<<<elemBlocks, TPB, 0, stream>>>(x, h, N * F);

    for (int l = 0; l < L; ++l) {
        // jumping-knowledge contribution of h_l (chunk l of mlpW1)
        k_accmm<<<rowBlocks, TPB, 0, stream>>>(h, mlpW1 + l * F * F, mlpb1, Yf, N, l == 0);
        // GIN aggregation: aggr = h + sum_{j->i} h_j
        k_copy_f<<<elemBlocks, TPB, 0, stream>>>(h, aggr, N * F);
        k_scatter<<<edgeBlocks, TPB, 0, stream>>>(src, dst, h, aggr, E);
        // mlp: Linear -> (BN stats) ; BN-apply+ReLU -> Linear -> ReLU
        k_gemm1<<<rowBlocks, TPB, 0, stream>>>(aggr, convW1 + l * F * F, convb1 + l * F,
                                               Ytmp, stats + l * 128, N);
        k_bn_gemm2<<<rowBlocks, TPB, 0, stream>>>(Ytmp, stats + l * 128, convg + l * F,
                                                  convbt + l * F, convW2 + l * F * F,
                                                  convb2 + l * F, h, N);
    }
    // last jump chunk (h_5)
    k_accmm<<<rowBlocks, TPB, 0, stream>>>(h, mlpW1 + L * F * F, mlpb1, Yf, N, 0);

    // head: BN stats over Yf, then BN+ReLU -> Linear -> pool
    k_colstats<<<rowBlocks, TPB, 0, stream>>>(Yf, stats + L * 128, N);
    k_final<<<rowBlocks, TPB, 0, stream>>>(Yf, stats + L * 128, mlpg, mlpbt, mlpW2, mlpb2,
                                           batch, pool, N);
    k_out<<<(G * F + TPB - 1) / TPB, TPB, 0, stream>>>(pool, (float*)d_out, G * F);
}